// Round 2
// baseline (167.510 us; speedup 1.0000x reference)
//
#include <hip/hip_runtime.h>

// SLAYER SNN forward, MI355X. Round 2.
// K1: conv1+pool1 as 9x9 stride-4 conv. 4 frames/block (1 frame per wave),
//     4 outputs/thread, bank-conflict-free permuted LDS tile (pitch 44).
// K2/K4: PSP+refractory scan, 64-thread blocks (full-CU spread).
// K3: conv2+pool2 as 4x4 stride-2 conv. 8 frames/block, 4 outputs/thread.
// K5: dense einsum, wave per (n,t).
// FP32 throughout; inner-sum expression shapes kept identical to round 1
// (bit-exact vs reference) so spike thresholds don't flip.

#define DECAY 0.9048374180359595f   // exp(-1/10)

// ---------------- K1 ----------------
// grid 1600 x 256. Output u1[t*16384 + n*256 + c*64 + i*8 + j].
// LDS tile per frame: [cin][40 rows][44 cols]; x row xr stored at row
// perm(xr+2), x col xc at col xc+4 (block-aligned halo).
// perm(r) = (r&3)*10 + (r>>2)  -> per-i bank stride 12 (2-way max, free).
__global__ __launch_bounds__(256) void k1(const float* __restrict__ x,
        const float* __restrict__ w1, const float* __restrict__ wp1,
        float* __restrict__ u1) {
    __shared__ __align__(16) float xs[4 * 2 * 40 * 44];   // 56.3 KB
    __shared__ __align__(16) float wl[864];               // [c][cin][e][12]
    __shared__ float wraw[200];
    const int tid = threadIdx.x;
    const int wave = tid >> 6, lane = tid & 63;

    for (int idx = tid; idx < 200; idx += 256) wraw[idx] = w1[idx];
    float4* fz = (float4*)(xs + wave * 3520);
    for (int m = lane; m < 880; m += 64) fz[m] = make_float4(0.f, 0.f, 0.f, 0.f);
    __syncthreads();

    const float p1 = wp1[0];
    for (int idx = tid; idx < 864; idx += 256) {
        const int f = idx % 12;
        const int rem = idx / 12;
        const int e = rem % 9;
        const int cc = rem / 9;
        float s = 0.f;
        if (f < 9) {
            int alo = e - 3; if (alo < 0) alo = 0;
            int ahi = e;     if (ahi > 4) ahi = 4;
            int blo = f - 3; if (blo < 0) blo = 0;
            int bhi = f;     if (bhi > 4) bhi = 4;
            for (int a = alo; a <= ahi; ++a)
                for (int b = blo; b <= bhi; ++b)
                    s += wraw[cc * 25 + a * 5 + b];
        }
        wl[idx] = s * p1;
    }

    // stage own frame (wave-private tile, but block-wide barriers for safety)
    const int frame = blockIdx.x * 4 + wave;      // = n*100 + t (x is n-major)
    const int n = frame / 100, t = frame % 100;
    float* xt = xs + wave * 3520;
    const float4* xg = (const float4*)(x + (size_t)frame * 2048);
    #pragma unroll
    for (int k = 0; k < 8; ++k) {
        const int m = lane + 64 * k;
        const float4 v = xg[m];
        const int li = 4 * m;
        const int cin = li >> 10;
        const int row = (li >> 5) & 31;
        const int col = li & 31;
        const int r = row + 2;
        const int pr = (r & 3) * 10 + (r >> 2);
        *(float4*)(xt + cin * 1760 + pr * 44 + col + 4) = v;
    }
    __syncthreads();

    // thread -> (c, i, jh): 4 outputs (c, i, 4*jh + 0..3)
    const int c = lane >> 4;
    const int i = (lane >> 1) & 7;
    const int jh = lane & 1;
    float acc[4] = {0.f, 0.f, 0.f, 0.f};
    const float* wb = wl + c * 216;
    const float* tb = xt + i * 44 + 16 * jh;
    #pragma unroll
    for (int cin = 0; cin < 2; ++cin) {
        #pragma unroll
        for (int e = 0; e < 9; ++e) {
            // x row needed = 4i+e-2, stored at perm(4i+e) = (e&3)*10+(e>>2) + i
            const int C = ((e & 3) * 10 + (e >> 2)) * 44 + cin * 1760;
            float xr[24];
            #pragma unroll
            for (int b = 0; b < 6; ++b)
                *(float4*)(xr + 4 * b) = *(const float4*)(tb + C + 4 * b);
            float wv[9];
            *(float4*)(wv)     = *(const float4*)(wb + cin * 108 + e * 12);
            *(float4*)(wv + 4) = *(const float4*)(wb + cin * 108 + e * 12 + 4);
            wv[8] = wb[cin * 108 + e * 12 + 8];
            #pragma unroll
            for (int jj = 0; jj < 4; ++jj) {
                const int o = 4 * jj + 2;      // reg idx of x col 4j-2
                acc[jj] += xr[o]*wv[0] + xr[o+1]*wv[1] + xr[o+2]*wv[2]
                         + xr[o+3]*wv[3] + xr[o+4]*wv[4] + xr[o+5]*wv[5]
                         + xr[o+6]*wv[6] + xr[o+7]*wv[7] + xr[o+8]*wv[8];
            }
        }
    }
    *(float4*)(u1 + (size_t)t * 16384 + n * 256 + c * 64 + i * 8 + 4 * jh) =
        make_float4(acc[0], acc[1], acc[2], acc[3]);
}

// ---------------- K2/K4: PSP + spike scan, in-place ----------------
__global__ __launch_bounds__(64) void k_scan(float* __restrict__ u, int stride) {
    const int id = blockIdx.x * 64 + threadIdx.x;
    const float a = DECAY;
    float psp = 0.f, r = 0.f;
    float* p = u + id;
    #pragma unroll 1
    for (int t0 = 0; t0 < 100; t0 += 10) {
        float v[10];
        #pragma unroll
        for (int k = 0; k < 10; ++k) v[k] = p[(size_t)(t0 + k) * stride];
        #pragma unroll
        for (int k = 0; k < 10; ++k) {
            psp = a * psp + v[k];
            const float vv = psp - r;
            const float s = (vv >= 1.f) ? 1.f : 0.f;
            r = a * (r + s);
            p[(size_t)(t0 + k) * stride] = s;
        }
    }
}

// ---------------- K3 ----------------
// grid 800 x 256 (8 frames/block, 32 threads/frame).
// LDS tile/frame: [cin][10 rows][16 cols], frame stride 660; row perm(r)=(r&1)*5+(r>>1),
// col offset +4. Weights wl[c2*68 + cin*16 + e*4 + f] (c2 stride 68 -> conflict-free).
__global__ __launch_bounds__(256) void k3(const float* __restrict__ s1,
        const float* __restrict__ w2, const float* __restrict__ wp2,
        float* __restrict__ u2) {
    __shared__ __align__(16) float xs[8 * 660];
    __shared__ __align__(16) float wl[8 * 68];
    __shared__ float wraw[288];
    const int tid = threadIdx.x;
    const int sub = tid >> 5;
    const int l = tid & 31;

    for (int idx = tid; idx < 288; idx += 256) wraw[idx] = w2[idx];
    float4* fz = (float4*)(xs + sub * 660);
    for (int m = l; m < 160; m += 32) fz[m] = make_float4(0.f, 0.f, 0.f, 0.f);
    __syncthreads();

    const float p2 = wp2[0];
    for (int idx = tid; idx < 512; idx += 256) {
        const int c2 = idx & 7;
        const int f = (idx >> 3) & 3;
        const int e = (idx >> 5) & 3;
        const int cin = idx >> 7;
        float s = 0.f;
        int alo = e - 1; if (alo < 0) alo = 0;
        int ahi = e;     if (ahi > 2) ahi = 2;
        int blo = f - 1; if (blo < 0) blo = 0;
        int bhi = f;     if (bhi > 2) bhi = 2;
        for (int aa = alo; aa <= ahi; ++aa)
            for (int bb = blo; bb <= bhi; ++bb)
                s += wraw[((c2 * 4 + cin) * 3 + aa) * 3 + bb];
        wl[c2 * 68 + cin * 16 + e * 4 + f] = s * p2;
    }

    const int frame = blockIdx.x * 8 + sub;       // = t*64 + n (s1 is t-major)
    const int t = frame >> 6, n = frame & 63;
    float* xt = xs + sub * 660;
    const float* fr = s1 + (size_t)t * 16384 + n * 256;
    {
        const int cin = l >> 3, row = l & 7;
        const int r = row + 1;
        const int pr = (r & 1) * 5 + (r >> 1);
        const float4 v0 = *(const float4*)(fr + cin * 64 + row * 8);
        const float4 v1 = *(const float4*)(fr + cin * 64 + row * 8 + 4);
        *(float4*)(xt + cin * 160 + pr * 16 + 4) = v0;
        *(float4*)(xt + cin * 160 + pr * 16 + 8) = v1;
    }
    __syncthreads();

    const int c2 = l >> 2, i = l & 3;
    float acc[4] = {0.f, 0.f, 0.f, 0.f};
    const float* wb = wl + c2 * 68;
    const float* tb = xt + i * 16;
    #pragma unroll
    for (int cin = 0; cin < 4; ++cin) {
        #pragma unroll
        for (int e = 0; e < 4; ++e) {
            // x row needed = 2i+e-1, stored at perm(2i+e) = (e&1)*5+(e>>1) + i
            const int C = cin * 160 + ((e & 1) * 5 + (e >> 1)) * 16;
            float xr[16];
            #pragma unroll
            for (int b = 0; b < 4; ++b)
                *(float4*)(xr + 4 * b) = *(const float4*)(tb + C + 4 * b);
            float wv[4];
            *(float4*)(wv) = *(const float4*)(wb + cin * 16 + e * 4);
            #pragma unroll
            for (int j = 0; j < 4; ++j) {
                #pragma unroll
                for (int f = 0; f < 4; ++f)
                    acc[j] += xr[2 * j + f + 3] * wv[f];
            }
        }
    }
    *(float4*)(u2 + (size_t)t * 8192 + n * 128 + c2 * 16 + i * 4) =
        make_float4(acc[0], acc[1], acc[2], acc[3]);
}

// ---------------- K5: dense einsum, one wave per (n,t) ----------------
__global__ __launch_bounds__(256) void k5_dense(const float* __restrict__ s2,
        const float* __restrict__ lw, float* __restrict__ out) {
    const int w = blockIdx.x * 4 + (threadIdx.x >> 6);   // 0..6399
    const int l = threadIdx.x & 63;
    const int n = w / 100, t = w % 100;
    const float* base = s2 + (size_t)t * 8192 + n * 128;
    const float sa = base[l], sb = base[64 + l];
    float a0 = sa * lw[l]       + sb * lw[64 + l];
    float a1 = sa * lw[128 + l] + sb * lw[192 + l];
    #pragma unroll
    for (int off = 32; off > 0; off >>= 1) {
        a0 += __shfl_down(a0, off);
        a1 += __shfl_down(a1, off);
    }
    if (l == 0) {
        out[n * 200 + t * 2]     = a0;
        out[n * 200 + t * 2 + 1] = a1;
    }
}

extern "C" void kernel_launch(void* const* d_in, const int* in_sizes, int n_in,
                              void* d_out, int out_size, void* d_ws, size_t ws_size,
                              hipStream_t stream) {
    const float* x   = (const float*)d_in[0];
    const float* w1  = (const float*)d_in[1];
    const float* w2  = (const float*)d_in[2];
    const float* lw  = (const float*)d_in[3];
    const float* wp1 = (const float*)d_in[4];
    const float* wp2 = (const float*)d_in[5];

    float* u1 = (float*)d_ws;            // 100*16384 floats (in-place -> s1)
    float* u2 = u1 + 1638400;            // 100*8192 floats  (in-place -> s2)
    float* out = (float*)d_out;          // (64,100,2)

    k1<<<1600, 256, 0, stream>>>(x, w1, wp1, u1);
    k_scan<<<256, 64, 0, stream>>>(u1, 16384);
    k3<<<800, 256, 0, stream>>>(u1, w2, wp2, u2);
    k_scan<<<128, 64, 0, stream>>>(u2, 8192);
    k5_dense<<<1600, 256, 0, stream>>>(u2, lw, out);
}

// Round 4
// 154.081 us; speedup vs baseline: 1.0872x; 1.0872x over previous
//
#include <hip/hip_runtime.h>

// SLAYER SNN forward, MI355X. Round 4.
// k0: fold conv+pool weights once -> wl1 (8x8 taps, SGPR-friendly layout), wl2.
// k1: conv1+pool1 as 8x8-tap stride-4 conv. 64-thr (1-wave) blocks, 4 frames/wave,
//     thread=(i,jh) computes all 4c x 4j outputs; weights via scalar loads;
//     cin-split 36x36 permuted tile (5.2 KB/frame) -> 7 blocks/CU.
//     perm(r)=(r&3)*9+(r>>2) bijective on r in 0..35; halo rows r{0,1,34,35}
//     -> prows {0,9,26,35} zeroed (the round-3 bug: 28/38 were missed).
// k2: PSP+refractory scan, 50-deep register batches.
// k3: conv2+pool2 as 4x4 stride-2 conv (round-2 body, fold hoisted to k0).
// k45: scan2 + dense fused; spikes stay in LDS; exact shuffle-tree reduction.
// FP32; summation expression shapes bit-compatible with rounds 1-2 (passed 0.0).

#define DECAY 0.9048374180359595f   // exp(-1/10)

// ---------------- k0: fold weights ----------------
// wl1[(cin*8 + e)*32 + c*8 + f], e,f in 0..7  (512 floats)
// wl2[c2*68 + cin*16 + e*4 + f]               (544 floats incl. unused pads)
__global__ __launch_bounds__(128) void k0_fold(const float* __restrict__ w1,
        const float* __restrict__ w2, const float* __restrict__ wp1,
        const float* __restrict__ wp2, float* __restrict__ wl1,
        float* __restrict__ wl2) {
    const int tid = threadIdx.x;
    const float p1 = wp1[0], p2 = wp2[0];
    for (int idx = tid; idx < 512; idx += 128) {
        const int f = idx & 7, c = (idx >> 3) & 3, e = (idx >> 5) & 7, cin = idx >> 8;
        const int cc = c * 2 + cin;
        int alo = e - 3; if (alo < 0) alo = 0;
        int ahi = e;     if (ahi > 4) ahi = 4;
        int blo = f - 3; if (blo < 0) blo = 0;
        int bhi = f;     if (bhi > 4) bhi = 4;
        float s = 0.f;
        for (int a = alo; a <= ahi; ++a)
            for (int b = blo; b <= bhi; ++b)
                s += w1[cc * 25 + a * 5 + b];
        wl1[(cin * 8 + e) * 32 + c * 8 + f] = s * p1;
    }
    for (int idx = tid; idx < 512; idx += 128) {
        const int c2 = idx & 7, f = (idx >> 3) & 3, e = (idx >> 5) & 3, cin = idx >> 7;
        int alo = e - 1; if (alo < 0) alo = 0;
        int ahi = e;     if (ahi > 2) ahi = 2;
        int blo = f - 1; if (blo < 0) blo = 0;
        int bhi = f;     if (bhi > 2) bhi = 2;
        float s = 0.f;
        for (int aa = alo; aa <= ahi; ++aa)
            for (int bb = blo; bb <= bhi; ++bb)
                s += w2[((c2 * 4 + cin) * 3 + aa) * 3 + bb];
        wl2[c2 * 68 + cin * 16 + e * 4 + f] = s * p2;
    }
}

// ---------------- k1: conv1+pool1, 8x8-tap stride-4 ----------------
// grid 1600 x 64. Tile/frame: 36 prow x 36 col (one cin at a time).
// Logical x row R (-2..33) at prow perm(R+2); logical col C (-2..33) at col C+2.
__global__ __launch_bounds__(64) void k1(const float* __restrict__ x,
        const float* __restrict__ wg, float* __restrict__ u1) {
    __shared__ __align__(16) float xs[4 * 1296];
    const int lane = threadIdx.x;
    const int fr = lane >> 4, l4 = lane & 15;
    const int i = (lane >> 1) & 7, jh = lane & 1;     // l4 = i*2 + jh
    const int frame = blockIdx.x * 4 + fr;            // = n*100 + t (x is n-major)
    const int n = frame / 100, t = frame % 100;
    float* xt = xs + fr * 1296;

    // zero halos once (stage never touches them; halo prows/cols are
    // disjoint from staged rows r=2..33 / cols 2..33 under the perm)
    #pragma unroll
    for (int m0 = 0; m0 < 48; m0 += 16) {             // 36 float4: rows r{0,1,34,35}
        const int m = m0 + l4;
        if (m < 36) {
            const int rr = m / 9, q4 = m % 9;
            const int pr = (rr == 0) ? 0 : (rr == 1) ? 9 : (rr == 2) ? 26 : 35;
            *(float4*)(xt + pr * 36 + q4 * 4) = make_float4(0.f, 0.f, 0.f, 0.f);
        }
    }
    #pragma unroll
    for (int m0 = 0; m0 < 80; m0 += 16) {             // 72 float2: cols {0,1},{34,35}
        const int m = m0 + l4;
        if (m < 72) {
            const int side = m & 1, pr = m >> 1;
            *(float2*)(xt + pr * 36 + side * 34) = make_float2(0.f, 0.f);
        }
    }

    float acc[4][4] = {{0.f}};   // [c][jj]
    const float* tb = xt + i * 36 + jh * 16;

    #pragma unroll 1
    for (int cin = 0; cin < 2; ++cin) {
        __syncthreads();
        // stage this cin's 32x32 block (1024 floats; 16 lanes/frame)
        const float4* xg = (const float4*)(x + (size_t)frame * 2048 + cin * 1024);
        #pragma unroll
        for (int q = 0; q < 16; ++q) {
            const int m = q * 16 + l4;                // float4 idx 0..255
            const float4 v = xg[m];
            const int li = 4 * m;
            const int row = li >> 5, col = li & 31;
            const int r = row + 2;
            const int pr = (r & 3) * 9 + (r >> 2);
            float* d = xt + pr * 36 + col + 2;        // col+2: 8B-aligned pairs
            *(float2*)(d)     = make_float2(v.x, v.y);
            *(float2*)(d + 2) = make_float2(v.z, v.w);
        }
        __syncthreads();

        #pragma unroll
        for (int e = 0; e < 8; ++e) {
            // x row 4i+e-2 -> prow (e&3)*9 + (e>>2) + i  (the +i is in tb)
            const int ro = ((e & 3) * 9 + (e >> 2)) * 36;
            float xr[20];
            #pragma unroll
            for (int b = 0; b < 5; ++b)
                *(float4*)(xr + 4 * b) = *(const float4*)(tb + ro + 4 * b);
            const float* wp = wg + (cin * 8 + e) * 32;   // wave-uniform -> s_load
            #pragma unroll
            for (int c = 0; c < 4; ++c) {
                #pragma unroll
                for (int jj = 0; jj < 4; ++jj) {
                    const int o = 4 * jj;
                    acc[c][jj] += xr[o]*wp[c*8]   + xr[o+1]*wp[c*8+1]
                                + xr[o+2]*wp[c*8+2] + xr[o+3]*wp[c*8+3]
                                + xr[o+4]*wp[c*8+4] + xr[o+5]*wp[c*8+5]
                                + xr[o+6]*wp[c*8+6] + xr[o+7]*wp[c*8+7];
                }
            }
        }
    }

    float* ob = u1 + (size_t)t * 16384 + n * 256 + i * 8 + jh * 4;
    #pragma unroll
    for (int c = 0; c < 4; ++c)
        *(float4*)(ob + c * 64) = make_float4(acc[c][0], acc[c][1], acc[c][2], acc[c][3]);
}

// ---------------- k2: scan1, 50-deep batches, in-place ----------------
__global__ __launch_bounds__(64, 2) void k2_scan(float* __restrict__ u) {
    const int id = blockIdx.x * 64 + threadIdx.x;
    const float a = DECAY;
    float psp = 0.f, r = 0.f;
    float* p = u + id;
    #pragma unroll 1
    for (int t0 = 0; t0 < 100; t0 += 50) {
        float v[50];
        #pragma unroll
        for (int k = 0; k < 50; ++k) v[k] = p[(size_t)(t0 + k) * 16384];
        #pragma unroll
        for (int k = 0; k < 50; ++k) {
            psp = a * psp + v[k];
            const float vv = psp - r;
            const float s = (vv >= 1.f) ? 1.f : 0.f;
            r = a * (r + s);
            p[(size_t)(t0 + k) * 16384] = s;
        }
    }
}

// ---------------- k3: conv2+pool2 as 4x4 stride-2 conv ----------------
// 8 frames/block (32 thr each). Tile/frame 660 floats, pitch 16, perm rows.
__global__ __launch_bounds__(256, 4) void k3(const float* __restrict__ s1,
        const float* __restrict__ wl2g, float* __restrict__ u2) {
    __shared__ __align__(16) float xs[8 * 660];
    __shared__ __align__(16) float wl[544];
    const int tid = threadIdx.x, sub = tid >> 5, l = tid & 31;

    for (int m = tid; m < 136; m += 256)
        *(float4*)(wl + 4 * m) = *(const float4*)(wl2g + 4 * m);

    float* xt = xs + sub * 660;
    float4* fz = (float4*)xt;
    for (int m = l; m < 160; m += 32) fz[m] = make_float4(0.f, 0.f, 0.f, 0.f);

    const int frame = blockIdx.x * 8 + sub;       // = t*64 + n (s1 is t-major)
    const int t = frame >> 6, n = frame & 63;
    const float* fr = s1 + (size_t)t * 16384 + n * 256;
    {   // stage 8x8x4cin; row r=row+1 at perm(r)=(r&1)*5+(r>>1), cols +4 phys
        const int cin = l >> 3, row = l & 7;
        const int r = row + 1;
        const int pr = (r & 1) * 5 + (r >> 1);
        const float4 v0 = *(const float4*)(fr + cin * 64 + row * 8);
        const float4 v1 = *(const float4*)(fr + cin * 64 + row * 8 + 4);
        *(float4*)(xt + cin * 160 + pr * 16 + 4) = v0;
        *(float4*)(xt + cin * 160 + pr * 16 + 8) = v1;
    }
    __syncthreads();

    const int c2 = l >> 2, i = l & 3;
    float acc[4] = {0.f, 0.f, 0.f, 0.f};
    const float* wb = wl + c2 * 68;
    const float* tb = xt + i * 16;
    #pragma unroll
    for (int cin = 0; cin < 4; ++cin) {
        #pragma unroll
        for (int e = 0; e < 4; ++e) {
            const int C = cin * 160 + ((e & 1) * 5 + (e >> 1)) * 16;
            float xr[16];
            #pragma unroll
            for (int b = 0; b < 4; ++b)
                *(float4*)(xr + 4 * b) = *(const float4*)(tb + C + 4 * b);
            float wv[4];
            *(float4*)(wv) = *(const float4*)(wb + cin * 16 + e * 4);
            #pragma unroll
            for (int j = 0; j < 4; ++j) {
                #pragma unroll
                for (int f = 0; f < 4; ++f)
                    acc[j] += xr[2 * j + f + 3] * wv[f];
            }
        }
    }
    *(float4*)(u2 + (size_t)t * 8192 + n * 128 + c2 * 16 + i * 4) =
        make_float4(acc[0], acc[1], acc[2], acc[3]);
}

// ---------------- k45: scan2 + dense, fused ----------------
// one block per n (64 blocks x 128 thr). Spikes stay in LDS; exact shuffle tree.
__global__ __launch_bounds__(128, 2) void k45(const float* __restrict__ u2,
        const float* __restrict__ lw, float* __restrict__ out) {
    __shared__ float ls[25 * 128];
    const int f = threadIdx.x, n = blockIdx.x;
    const int wave = f >> 6, l = f & 63;
    const float a = DECAY;
    const float w0 = lw[l], w1v = lw[64 + l], w2v = lw[128 + l], w3v = lw[192 + l];
    float psp = 0.f, r = 0.f;
    const float* p = u2 + n * 128 + f;
    #pragma unroll 1
    for (int t0 = 0; t0 < 100; t0 += 25) {
        float v[25];
        #pragma unroll
        for (int k = 0; k < 25; ++k) v[k] = p[(size_t)(t0 + k) * 8192];
        #pragma unroll
        for (int k = 0; k < 25; ++k) {
            psp = a * psp + v[k];
            const float vv = psp - r;
            const float s = (vv >= 1.f) ? 1.f : 0.f;
            r = a * (r + s);
            ls[k * 128 + f] = s;
        }
        __syncthreads();
        const int base = wave ? 13 : 0, cnt = wave ? 12 : 13;
        for (int q = 0; q < cnt; ++q) {
            const int k = base + q;
            const float sa = ls[k * 128 + l], sb = ls[k * 128 + 64 + l];
            float a0 = sa * w0 + sb * w1v;
            float a1 = sa * w2v + sb * w3v;
            #pragma unroll
            for (int off = 32; off > 0; off >>= 1) {
                a0 += __shfl_down(a0, off);
                a1 += __shfl_down(a1, off);
            }
            if (l == 0) {
                const int tt = t0 + k;
                out[n * 200 + tt * 2]     = a0;
                out[n * 200 + tt * 2 + 1] = a1;
            }
        }
        __syncthreads();
    }
}

extern "C" void kernel_launch(void* const* d_in, const int* in_sizes, int n_in,
                              void* d_out, int out_size, void* d_ws, size_t ws_size,
                              hipStream_t stream) {
    const float* x   = (const float*)d_in[0];
    const float* w1  = (const float*)d_in[1];
    const float* w2  = (const float*)d_in[2];
    const float* lw  = (const float*)d_in[3];
    const float* wp1 = (const float*)d_in[4];
    const float* wp2 = (const float*)d_in[5];

    float* u1  = (float*)d_ws;           // 1,638,400 floats (in-place -> s1)
    float* u2  = u1 + 1638400;           //   819,200 floats (pre-scan only)
    float* wl1 = u2 + 819200;            //       512 floats
    float* wl2 = wl1 + 512;              //       544 floats
    float* out = (float*)d_out;          // (64,100,2)

    k0_fold<<<1, 128, 0, stream>>>(w1, w2, wp1, wp2, wl1, wl2);
    k1<<<1600, 64, 0, stream>>>(x, wl1, u1);
    k2_scan<<<256, 64, 0, stream>>>(u1);
    k3<<<800, 256, 0, stream>>>(u1, wl2, u2);
    k45<<<64, 128, 0, stream>>>(u2, lw, out);
}